// Round 15
// baseline (248.353 us; speedup 1.0000x reference)
//
#include <hip/hip_runtime.h>
#include <hip/hip_fp16.h>

// ---------------------------------------------------------------------------
// LinearAggActor R34 (R33/R30 + agg-first block order in hop_k):
//  - math (verified R2-R16): z0 = t2@(w3@w1)+b3@w1 (16-dim); z_k = A^k z0;
//    logits = cvec + sum_k relu(relu(z_k+b1)@w2+b2) @ M_k ; softmax.
//  - R31 post-mortem: 1-node/wave agg regressed (274.7). LAW: concurrent
//    independent chains/CU is the currency.
//  - R32 post-mortem: j-parallel hop field regressed (262.2): heavy field
//    waves are the VALU/mem overlap partner for agg (m114) — keep them.
//  - R34: hop_k block order SWAPPED: agg role at blocks [0,AB) (the
//    latency-bound critical path starts dispatching at t=0), field role at
//    [AB,AB+FB) (backfills behind in-flight agg waves). Same wave mix as
//    R30 — only issue order changes. Expected -1..-2us/hop.
//  - R30 config kept (peaked local optimum):
//    * csr2||proj merged role-split launch (both low-VGPR after R29)
//    * j-parallel proj + fieldsoft (16 lanes/node, shfl stages, xor-reduce)
//    * hop: thread-per-node field + 4-nodes/wave agg, tier-sorted
//      csrp_s/nd_s 2-epoch chain, (256,4)
//    * fp16 z rows (32B) + uint2 gathers, fp32 accumulate
//  - build (R10-15): binfill multisplit + setup on idle CUs; sentinel row n.
// ---------------------------------------------------------------------------

#define NB2MAX 400   // bins of 128 dsts: supports n <= 51200
#define NBLK   256   // binfill blocks
#define CAP2   32    // LDS staging per bin
#define CAPC   48    // per-(bin,block) cell capacity (mean 16, +8 sigma)
#define CAPB   6144  // per-bin dense CSR region (overflow tails only)
#define OVCAP  1024  // per-bin overflow region (statistically unused)
#define LCAP   6144  // csr2 per-bin LDS capacity (mean 4096, +32 sigma)
#define CAPN   64    // padded slots per node (mean 32, +5.7 sigma)

// blocks [0,NBLK): multisplit into private (bin,block) cells; packed
// (dloc<<16|src); LDS cursors; no global atomics on the hot path.
// blocks [NBLK, NBLK+9): setup role (R10-verified).
__global__ __launch_bounds__(1024) void binfill_k(
    const int* __restrict__ src, const int* __restrict__ dst, int E, int n,
    int* __restrict__ gcur, int* __restrict__ ovbuf,
    int* __restrict__ bins, int* __restrict__ cnts,
    const float* __restrict__ w1, const float* __restrict__ w3,
    const float* __restrict__ b3, const float* __restrict__ fc1w,
    const float* __restrict__ fc1b, const float* __restrict__ fc2w,
    const float* __restrict__ fc2b,
    float* __restrict__ M, float* __restrict__ cvec,
    float* __restrict__ W31, float* __restrict__ c31) {
    __shared__ int lbuf[NB2MAX * CAP2];
    __shared__ int lcnt[NB2MAX];
    __shared__ int lflush[NB2MAX];
    int tid = threadIdx.x;
    int NB = (n + 127) >> 7;

    if ((int)blockIdx.x >= NBLK) {
        // ---------------- setup role ----------------
        float* fl = (float*)lbuf;   // LDS reuse
        int s = (int)blockIdx.x - NBLK;
        if (s == 0) {
            if (tid < 256) {
                int i = tid >> 4, j = tid & 15;
                float a = 0.f;
                for (int g = 0; g < 64; g++) a += w3[i * 64 + g] * w1[g * 16 + j];
                W31[tid] = a;
            } else if (tid < 272) {
                int j = tid - 256;
                float a = 0.f;
                for (int g = 0; g < 64; g++) a += b3[g] * w1[g * 16 + j];
                c31[j] = a;
            } else if (tid >= 320 && tid < 384) {
                int h = tid - 320;
                float a = 0.f;
                for (int r = 0; r < 512; r++) a += b3[r & 63] * fc1w[r * 64 + h];
                fl[h] = a;   // u[h]
            }
            __syncthreads();
            if (tid < 8) {
                float a = fc2b[tid];
                for (int h = 0; h < 64; h++) a += (fc1b[h] + fl[h]) * fc2w[h * 8 + tid];
                cvec[tid] = a;
            }
        } else {
            int k = s - 1;
            {   // Q_k: one elem per thread
                int i = tid >> 6, h = tid & 63;
                float a = 0.f;
                const float* f1 = fc1w + (size_t)(k * 64) * 64 + h;
                for (int g = 0; g < 64; g++) a += w3[i * 64 + g] * f1[g * 64];
                fl[i * 64 + h] = a;
            }
            __syncthreads();
            if (tid < 128) {
                int i = tid >> 3, j = tid & 7;
                float a = 0.f;
                for (int h = 0; h < 64; h++) a += fl[i * 64 + h] * fc2w[h * 8 + j];
                M[k * 128 + i * 8 + j] = a;
            }
        }
        return;
    }

    // ---------------- binfill role ----------------
    for (int b = tid; b < NB; b += 1024) { lcnt[b] = 0; lflush[b] = 0; }
    __syncthreads();
    int blk = blockIdx.x;
    int chunk = (E + NBLK - 1) / NBLK;
    int beg = blk * chunk;
    int end = beg + chunk; if (end > E) end = E;
    for (int t0 = beg; t0 < end; t0 += 1024) {
        int e = t0 + tid;
        if (e < end) {
            int d = dst[e], s = src[e];
            if ((unsigned)d < (unsigned)n && (unsigned)s < (unsigned)n) {
                int b = d >> 7;
                int pk = ((d & 127) << 16) | s;
                int pos = atomicAdd(&lcnt[b], 1);
                if (pos < CAP2) lbuf[b * CAP2 + pos] = pk;
                else {  // statistically never
                    int p = atomicAdd(&gcur[b], 1);
                    if (p < OVCAP) ovbuf[b * OVCAP + p] = pk;
                }
            }
        }
        __syncthreads();
        for (int b = tid; b < NB; b += 1024) {
            int cnt = lcnt[b]; if (cnt > CAP2) cnt = CAP2;
            int fl2 = lflush[b];
            size_t cell = ((size_t)b * NBLK + blk) * CAPC;
            int base = 0;
            while (cnt - base >= 16) {
                if (fl2 + 16 <= CAPC) {
                    int* dp = bins + cell + fl2;
                    #pragma unroll
                    for (int q = 0; q < 16; q++) dp[q] = lbuf[b * CAP2 + base + q];
                    fl2 += 16;
                } else {  // cell overflow (statistically never)
                    int p = atomicAdd(&gcur[b], 16);
                    for (int q = 0; q < 16; q++)
                        if (p + q < OVCAP) ovbuf[b * OVCAP + p + q] = lbuf[b * CAP2 + base + q];
                }
                base += 16;
            }
            int rem = cnt - base;
            if (base > 0)
                for (int q = 0; q < rem; q++) lbuf[b * CAP2 + q] = lbuf[b * CAP2 + base + q];
            lcnt[b] = rem; lflush[b] = fl2;
        }
        __syncthreads();
    }
    for (int b = tid; b < NB; b += 1024) {
        int cnt = lcnt[b]; if (cnt > CAP2) cnt = CAP2;
        int fl2 = lflush[b];
        size_t cell = ((size_t)b * NBLK + blk) * CAPC;
        if (fl2 + cnt <= CAPC) {
            for (int q = 0; q < cnt; q++) bins[cell + fl2 + q] = lbuf[b * CAP2 + q];
            fl2 += cnt;
        } else {
            int p = atomicAdd(&gcur[b], cnt);
            for (int q = 0; q < cnt; q++)
                if (p + q < OVCAP) ovbuf[b * OVCAP + p + q] = lbuf[b * CAP2 + q];
        }
        cnts[(size_t)blk * NB + b] = fl2;
    }
}

// Merged launch (R30a). Blocks [0,NB): csr2 role (low VGPR, latency-bound,
// hides under proj's block sea). Blocks [NB, NB+FBJ): j-parallel proj role.
struct SmemC {   // csr2 role
    int hist[128], pref[128], cur[128], slot[128];
    int scnt[NBLK];
    int lbuf[LCAP];
    int sov;
    int ccnt[3], cbase[3];
};
struct SmemP {   // proj role
    float sx[16 * 68];
    float sw1[1024], sw2[256], sW[256], sM[128];
    float sb1[16], sb2[16], sc[16], scv[8];
};
union SmemU { SmemC c; SmemP p; };

__global__ __launch_bounds__(256) void csr2proj_k(
    const int* __restrict__ bins, const int* __restrict__ cnts,
    const int* __restrict__ gcur, const int* __restrict__ ovbuf,
    unsigned short* __restrict__ csrp_s, int2* __restrict__ nd_s,
    int* __restrict__ csr, int2* __restrict__ be, int* __restrict__ lcnt3,
    const float* __restrict__ x, __half* __restrict__ z0, __half* __restrict__ z1,
    float* __restrict__ logits,
    const float* __restrict__ w1, const float* __restrict__ b1,
    const float* __restrict__ w2, const float* __restrict__ b2,
    const float* __restrict__ W31, const float* __restrict__ c31,
    const float* __restrict__ M0, const float* __restrict__ cvec,
    int n, int NBARG) {
    __shared__ SmemU smem;
    int tid = threadIdx.x;
    if ((int)blockIdx.x < NBARG) {
        // ======================= csr2 role =======================
        SmemC& sc_ = smem.c;
        int NB = NBARG;
        int b = blockIdx.x;
        if (tid < 128) { sc_.hist[tid] = 0; sc_.cur[tid] = 0; }
        if (tid < 3) sc_.ccnt[tid] = 0;
        sc_.scnt[tid] = cnts[(size_t)tid * NB + b];
        if (tid == 0) {
            int g = gcur[b];
            sc_.sov = g < 0 ? 0 : (g > OVCAP ? OVCAP : g);
        }
        __syncthreads();
        {   // pass 1: histogram of dst-local
            int c = sc_.scnt[tid];
            size_t cell = ((size_t)b * NBLK + tid) * CAPC;
            for (int i = 0; i < c; i++) atomicAdd(&sc_.hist[bins[cell + i] >> 16], 1);
        }
        if (tid == 0)
            for (int i = 0; i < sc_.sov; i++)
                atomicAdd(&sc_.hist[ovbuf[b * OVCAP + i] >> 16], 1);
        __syncthreads();
        if (tid == 0) {
            int r = 0;
            for (int i = 0; i < 128; i++) { sc_.pref[i] = r; r += sc_.hist[i]; }
        }
        __syncthreads();
        {   // pass 2: place into LDS (bin-locally dense, sorted by dst)
            int c = sc_.scnt[tid];
            size_t cell = ((size_t)b * NBLK + tid) * CAPC;
            for (int i = 0; i < c; i++) {
                int pk = bins[cell + i];
                int dl = pk >> 16;
                int pos = sc_.pref[dl] + atomicAdd(&sc_.cur[dl], 1);
                if (pos < LCAP) sc_.lbuf[pos] = pk & 0xffff;
            }
        }
        if (tid == 0) {
            for (int i = 0; i < sc_.sov; i++) {
                int pk = ovbuf[b * OVCAP + i];
                int dl = pk >> 16;
                int pos = sc_.pref[dl] + atomicAdd(&sc_.cur[dl], 1);
                if (pos < LCAP) sc_.lbuf[pos] = pk & 0xffff;
            }
        }
        __syncthreads();
        // tier classification -> global sorted slot per node
        int myc = -1, lpos = 0;
        if (tid < 128) {
            int d = (b << 7) + tid;
            if (d < n) {
                int cnt = sc_.hist[tid];
                myc = cnt <= 32 ? 0 : (cnt <= 48 ? 1 : 2);
                lpos = atomicAdd(&sc_.ccnt[myc], 1);
            }
        }
        __syncthreads();
        if (tid < 3) sc_.cbase[tid] = atomicAdd(&lcnt3[tid], sc_.ccnt[tid]);
        __syncthreads();
        if (myc >= 0) {
            int d = (b << 7) + tid;
            int cnt = sc_.hist[tid];
            int s = myc * n + sc_.cbase[myc] + lpos;   // region base myc*n
            sc_.slot[tid] = s;
            nd_s[s] = make_int2(d, cnt);
            if (cnt > CAPN) {   // rare tail -> dense region + be (premult x4)
                int s0 = b * CAPB + sc_.pref[tid];
                be[d] = make_int2(s0 + CAPN, s0 + cnt);
                for (int j = CAPN; j < cnt; j++)
                    csr[s0 + j] = sc_.lbuf[sc_.pref[tid] + j] << 2;
            }
        }
        __syncthreads();
        // permuted padded ushort CSR into sorted row; sentinel = n (zero row)
        for (int q = tid; q < 128 * CAPN; q += 256) {
            int dl = q >> 6, j = q & 63;
            int d = (b << 7) + dl;
            if (d >= n) break;
            int cnt = sc_.hist[dl];
            int v = (j < cnt) ? sc_.lbuf[sc_.pref[dl] + j] : n;
            int pos = ((j & 3) << 4) | (j >> 2);
            csrp_s[(size_t)sc_.slot[dl] * CAPN + pos] = (unsigned short)v;
        }
        return;
    }
    // ======================= proj role (j-parallel, R29) =======================
    SmemP& sp = smem.p;
    for (int i = tid; i < 1024; i += 256) sp.sw1[i] = w1[i];
    sp.sw2[tid] = w2[tid];
    sp.sW[tid] = W31[tid];
    if (tid < 128) sp.sM[tid] = M0[tid];
    if (tid < 16) { sp.sb1[tid] = b1[tid]; sp.sb2[tid] = b2[tid]; sp.sc[tid] = c31[tid]; }
    if (tid < 8) sp.scv[tid] = cvec[tid];
    if ((int)blockIdx.x == NBARG && tid < 16) {   // zero sentinel row n
        ((unsigned short*)z0)[(size_t)n * 16 + tid] = 0;
        ((unsigned short*)z1)[(size_t)n * 16 + tid] = 0;
    }
    int node0 = ((int)blockIdx.x - NBARG) * 16;
    {   // stage x: 16 rows x 64 floats, coalesced float4
        int r = tid >> 4, c4 = tid & 15;
        if (node0 + r < n) {
            float4 v = ((const float4*)(x + (size_t)(node0 + r) * 64))[c4];
            float* dstp = sp.sx + r * 68 + c4 * 4;
            dstp[0] = v.x; dstp[1] = v.y; dstp[2] = v.z; dstp[3] = v.w;
        }
    }
    __syncthreads();
    int nl = tid >> 4, jj = tid & 15;
    int node = node0 + nl;
    if (node >= n) return;
    float t1 = 0.f;
    const float* xr = sp.sx + nl * 68;
    #pragma unroll
    for (int g = 0; g < 64; g++) t1 += xr[g] * sp.sw1[g * 16 + jj];
    t1 = fmaxf(t1 + sp.sb1[jj], 0.f);
    float t2 = sp.sb2[jj];
    #pragma unroll
    for (int i = 0; i < 16; i++) t2 += __shfl(t1, i, 16) * sp.sw2[i * 16 + jj];
    t2 = fmaxf(t2, 0.f);
    float zv = sp.sc[jj];
    #pragma unroll
    for (int i = 0; i < 16; i++) zv += __shfl(t2, i, 16) * sp.sW[i * 16 + jj];
    z0[(size_t)node * 16 + jj] = __float2half(zv);
    float hv = fmaxf(zv + sp.sb1[jj], 0.f);
    float f2 = sp.sb2[jj];
    #pragma unroll
    for (int i = 0; i < 16; i++) f2 += __shfl(hv, i, 16) * sp.sw2[i * 16 + jj];
    f2 = fmaxf(f2, 0.f);
    float p0 = f2 * sp.sM[jj * 8 + 0], p1 = f2 * sp.sM[jj * 8 + 1];
    float p2 = f2 * sp.sM[jj * 8 + 2], p3 = f2 * sp.sM[jj * 8 + 3];
    float p4 = f2 * sp.sM[jj * 8 + 4], p5 = f2 * sp.sM[jj * 8 + 5];
    float p6 = f2 * sp.sM[jj * 8 + 6], p7 = f2 * sp.sM[jj * 8 + 7];
    #pragma unroll
    for (int off = 1; off < 16; off <<= 1) {
        p0 += __shfl_xor(p0, off, 16); p1 += __shfl_xor(p1, off, 16);
        p2 += __shfl_xor(p2, off, 16); p3 += __shfl_xor(p3, off, 16);
        p4 += __shfl_xor(p4, off, 16); p5 += __shfl_xor(p5, off, 16);
        p6 += __shfl_xor(p6, off, 16); p7 += __shfl_xor(p7, off, 16);
    }
    if (jj < 8) {   // compile-time select chain (no runtime reg indexing)
        float myp = jj == 0 ? p0 : jj == 1 ? p1 : jj == 2 ? p2 : jj == 3 ? p3
                  : jj == 4 ? p4 : jj == 5 ? p5 : jj == 6 ? p6 : p7;
        logits[(size_t)node * 8 + jj] = sp.scv[jj] + myp;
    }
}

// unpack one uint2 (4 halfs = one channel quad) and accumulate
__device__ __forceinline__ void acc_row(uint2 u, float& ax, float& ay,
                                        float& az, float& aw) {
    __half2 p = *reinterpret_cast<const __half2*>(&u.x);
    __half2 q = *reinterpret_cast<const __half2*>(&u.y);
    float2 f = __half22float2(p), g = __half22float2(q);
    ax += f.x; ay += f.y; az += g.x; aw += g.y;
}

// One launch per hop. R34 ORDER SWAP: blocks [0,AB) = agg (critical path
// dispatches at t=0); blocks [AB,..) = field(z_k) thread-per-node (VALU-
// heavy overlap partner — backfills behind in-flight agg waves; do NOT
// j-parallelize, R32 measured -27us).
__global__ __launch_bounds__(256, 4) void hop_k(
    const __half* __restrict__ zin, __half* __restrict__ zout,
    float* __restrict__ logits,
    const unsigned short* __restrict__ csrp_s, const int2* __restrict__ nd_s,
    const int2* __restrict__ be, const int* __restrict__ csr,
    const int* __restrict__ lcnt3,
    const float* __restrict__ w2, const float* __restrict__ b1,
    const float* __restrict__ b2, const float* __restrict__ M, int n, int AB) {
    __shared__ float sw2[256], sM[128], sb1[16], sb2[16];
    int tid = threadIdx.x;
    if ((int)blockIdx.x >= AB) {
        // ---- field role (thread-per-node) ----
        sw2[tid] = w2[tid];
        if (tid < 128) sM[tid] = M[tid];
        if (tid < 16) { sb1[tid] = b1[tid]; sb2[tid] = b2[tid]; }
        __syncthreads();
        int nid = ((int)blockIdx.x - AB) * 256 + tid;
        if (nid >= n) return;
        float h[16];
        const __half2* zp = (const __half2*)(zin + (size_t)nid * 16);
        #pragma unroll
        for (int q = 0; q < 8; q++) {
            float2 f = __half22float2(zp[q]);
            h[2 * q] = f.x; h[2 * q + 1] = f.y;
        }
        #pragma unroll
        for (int i = 0; i < 16; i++) h[i] = fmaxf(h[i] + sb1[i], 0.f);
        float t2[16];
        #pragma unroll
        for (int j = 0; j < 16; j++) {
            float a = sb2[j];
            #pragma unroll
            for (int i = 0; i < 16; i++) a += h[i] * sw2[i * 16 + j];
            t2[j] = fmaxf(a, 0.f);
        }
        float* lp = logits + (size_t)nid * 8;
        #pragma unroll
        for (int j = 0; j < 8; j++) {
            float l = 0.f;
            #pragma unroll
            for (int i = 0; i < 16; i++) l += t2[i] * sM[i * 8 + j];
            lp[j] += l;
        }
        return;
    }
    // ---- agg role: 4 nodes per wave, tier-sorted direct rows ----
    int wave = tid >> 6;
    int lane = tid & 63;
    int quarter = lane >> 4;              // which node of the 4
    int l16 = lane & 15;
    int t4 = l16 >> 2, ch = l16 & 3;      // slot-group 0..3, chan-quad 0..3
    int idx = ((int)blockIdx.x * 4 + wave) * 4 + quarter;
    if (idx >= n) return;
    int ns = lcnt3[0], nm = lcnt3[1];     // uniform scalar loads
    int tier; size_t row;
    if (idx < ns)           { tier = 0; row = (size_t)idx; }
    else if (idx < ns + nm) { tier = 1; row = (size_t)n + (idx - ns); }
    else                    { tier = 2; row = 2 * (size_t)n + (idx - ns - nm); }
    int2 nd = nd_s[row];                  // {node, deg} — same epoch as ip
    int node = nd.x, degi = nd.y;
    const uint4* ip = (const uint4*)(csrp_s + (row << 6));
    uint4 pa = ip[t4 * 2];                // sorted slots j = t4, t4+4, ..., t4+28
    int r0 = pa.x & 0xffff, r1 = pa.x >> 16;
    int r2 = pa.y & 0xffff, r3 = pa.y >> 16;
    int r4 = pa.z & 0xffff, r5 = pa.z >> 16;
    int r6 = pa.w & 0xffff, r7 = pa.w >> 16;
    const uint2* z2 = (const uint2*)zin;  // row stride = 4 uint2 (32B)
    uint2 u0 = z2[((size_t)r0 << 2) + ch];   // sentinel n -> zero row
    uint2 u1 = z2[((size_t)r1 << 2) + ch];
    uint2 u2 = z2[((size_t)r2 << 2) + ch];
    uint2 u3 = z2[((size_t)r3 << 2) + ch];
    uint2 u4 = z2[((size_t)r4 << 2) + ch];
    uint2 u5 = z2[((size_t)r5 << 2) + ch];
    uint2 u6 = z2[((size_t)r6 << 2) + ch];
    uint2 u7 = z2[((size_t)r7 << 2) + ch];
    float ax = 0.f, ay = 0.f, az = 0.f, aw = 0.f;
    acc_row(u0, ax, ay, az, aw); acc_row(u1, ax, ay, az, aw);
    acc_row(u2, ax, ay, az, aw); acc_row(u3, ax, ay, az, aw);
    acc_row(u4, ax, ay, az, aw); acc_row(u5, ax, ay, az, aw);
    acc_row(u6, ax, ay, az, aw); acc_row(u7, ax, ay, az, aw);
    if (tier >= 1) {
        uint4 pb = ip[t4 * 2 + 1];        // sorted slots j = t4+32..t4+60
        int r8 = pb.x & 0xffff, r9 = pb.x >> 16;
        int rA = pb.y & 0xffff, rB = pb.y >> 16;
        uint2 u8 = z2[((size_t)r8 << 2) + ch];
        uint2 u9 = z2[((size_t)r9 << 2) + ch];
        uint2 uA = z2[((size_t)rA << 2) + ch];
        uint2 uB = z2[((size_t)rB << 2) + ch];
        acc_row(u8, ax, ay, az, aw); acc_row(u9, ax, ay, az, aw);
        acc_row(uA, ax, ay, az, aw); acc_row(uB, ax, ay, az, aw);
        if (tier == 2) {
            int rC = pb.z & 0xffff, rD = pb.z >> 16;
            int rE = pb.w & 0xffff, rF = pb.w >> 16;
            uint2 uC = z2[((size_t)rC << 2) + ch];
            uint2 uD = z2[((size_t)rD << 2) + ch];
            uint2 uE = z2[((size_t)rE << 2) + ch];
            uint2 uF = z2[((size_t)rF << 2) + ch];
            acc_row(uC, ax, ay, az, aw); acc_row(uD, ax, ay, az, aw);
            acc_row(uE, ax, ay, az, aw); acc_row(uF, ax, ay, az, aw);
            if (degi > CAPN) {            // rare tail via dense csr (4 slots)
                int2 r = be[node];
                for (int q = r.x + t4; q < r.y; q += 4) {
                    uint2 u = z2[(size_t)csr[q] + ch];   // csr premult x4
                    acc_row(u, ax, ay, az, aw);
                }
            }
        }
    }
    // reduce over 4 slot-groups within this 16-lane quarter
    #pragma unroll
    for (int off = 8; off >= 4; off >>= 1) {
        ax += __shfl_down(ax, off, 16);
        ay += __shfl_down(ay, off, 16);
        az += __shfl_down(az, off, 16);
        aw += __shfl_down(aw, off, 16);
    }
    if (l16 < 4) {
        float inv = 1.f / (float)(degi > 0 ? degi : 1);
        __half2 h01 = __floats2half2_rn(ax * inv, ay * inv);
        __half2 h23 = __floats2half2_rn(az * inv, aw * inv);
        uint2 w;
        w.x = *reinterpret_cast<unsigned int*>(&h01);
        w.y = *reinterpret_cast<unsigned int*>(&h23);
        ((uint2*)(zout + (size_t)node * 16))[l16] = w;
    }
}

// final (R30b): logits += field(z7, M7); softmax. J-PARALLEL, 16 lanes/node.
__global__ __launch_bounds__(256, 4) void fieldsoft_k(
    const __half* __restrict__ z, float* __restrict__ logits,
    const float* __restrict__ w2, const float* __restrict__ b1,
    const float* __restrict__ b2, const float* __restrict__ M, int n) {
    __shared__ float sw2[256], sM[128], sb1[16], sb2[16];
    int tid = threadIdx.x;
    sw2[tid] = w2[tid];
    if (tid < 128) sM[tid] = M[tid];
    if (tid < 16) { sb1[tid] = b1[tid]; sb2[tid] = b2[tid]; }
    __syncthreads();
    int nl = tid >> 4, jj = tid & 15;
    int node = blockIdx.x * 16 + nl;
    if (node >= n) return;
    // lane jj loads z[node][jj]: 32B/node, contiguous 128B per 4-node wave
    float zv = __half2float(z[(size_t)node * 16 + jj]);
    float hv = fmaxf(zv + sb1[jj], 0.f);
    float t2 = sb2[jj];
    #pragma unroll
    for (int i = 0; i < 16; i++) t2 += __shfl(hv, i, 16) * sw2[i * 16 + jj];
    t2 = fmaxf(t2, 0.f);
    float p0 = t2 * sM[jj * 8 + 0], p1 = t2 * sM[jj * 8 + 1];
    float p2 = t2 * sM[jj * 8 + 2], p3 = t2 * sM[jj * 8 + 3];
    float p4 = t2 * sM[jj * 8 + 4], p5 = t2 * sM[jj * 8 + 5];
    float p6 = t2 * sM[jj * 8 + 6], p7 = t2 * sM[jj * 8 + 7];
    #pragma unroll
    for (int off = 1; off < 16; off <<= 1) {
        p0 += __shfl_xor(p0, off, 16); p1 += __shfl_xor(p1, off, 16);
        p2 += __shfl_xor(p2, off, 16); p3 += __shfl_xor(p3, off, 16);
        p4 += __shfl_xor(p4, off, 16); p5 += __shfl_xor(p5, off, 16);
        p6 += __shfl_xor(p6, off, 16); p7 += __shfl_xor(p7, off, 16);
    }
    // all 16 lanes now hold the full p0..p7. Lane jj works on logit q=jj&7
    // (lanes 8-15 mirror 0-7 so width-8 shuffles are well-defined).
    int q = jj & 7;
    float myp = q == 0 ? p0 : q == 1 ? p1 : q == 2 ? p2 : q == 3 ? p3
              : q == 4 ? p4 : q == 5 ? p5 : q == 6 ? p6 : p7;
    float lg = myp + logits[(size_t)node * 8 + q];
    float m = lg;
    m = fmaxf(m, __shfl_xor(m, 1, 8));
    m = fmaxf(m, __shfl_xor(m, 2, 8));
    m = fmaxf(m, __shfl_xor(m, 4, 8));
    float e = expf(lg - m);
    float s = e;
    s += __shfl_xor(s, 1, 8);
    s += __shfl_xor(s, 2, 8);
    s += __shfl_xor(s, 4, 8);
    if (jj < 8) logits[(size_t)node * 8 + jj] = e / s;
}

extern "C" void kernel_launch(void* const* d_in, const int* in_sizes, int n_in,
                              void* d_out, int out_size, void* d_ws, size_t ws_size,
                              hipStream_t stream) {
    const float* x    = (const float*)d_in[0];
    const int*   ei   = (const int*)d_in[1];
    const float* w1   = (const float*)d_in[2];
    const float* b1   = (const float*)d_in[3];
    const float* w2   = (const float*)d_in[4];
    const float* b2   = (const float*)d_in[5];
    const float* w3   = (const float*)d_in[6];
    const float* b3   = (const float*)d_in[7];
    const float* fc1w = (const float*)d_in[8];
    const float* fc1b = (const float*)d_in[9];
    const float* fc2w = (const float*)d_in[10];
    const float* fc2b = (const float*)d_in[11];
    float* out = (float*)d_out;

    int n = in_sizes[0] / 64;
    int E = in_sizes[1] / 2;
    int NB = (n + 127) >> 7;   // 391 for n=50000; NB <= NB2MAX
    const int* src = ei;
    const int* dst = ei + E;

    char* ws = (char*)d_ws;
    auto carve = [&](size_t bytes) {
        char* p = ws;
        ws += (bytes + 255) & ~((size_t)255);
        return p;
    };
    int*   gcur    = (int*)carve((size_t)NB * 4);
    int*   lcnt3   = (int*)carve(16);                 // contiguous after gcur pad
    int*   ovbuf   = (int*)carve((size_t)NB * OVCAP * 4);
    int*   binsbuf = (int*)carve((size_t)NB * NBLK * CAPC * 4);
    int*   cnts    = (int*)carve((size_t)NBLK * NB * 4);
    unsigned short* csrp_s = (unsigned short*)carve((size_t)3 * n * CAPN * 2); // tier-sorted
    int2*  nd_s    = (int2*)carve((size_t)3 * n * 8);                          // {node,deg}
    int*   csr     = (int*)carve((size_t)NB * CAPB * 4);
    int2*  be      = (int2*)carve((size_t)n * 8);
    __half* buf0   = (__half*)carve((size_t)(n + 1) * 16 * 2);  // +1 zero row
    __half* buf1   = (__half*)carve((size_t)(n + 1) * 16 * 2);
    float* M       = (float*)carve(1024 * 4);
    float* cvec    = (float*)carve(8 * 4);
    float* W31     = (float*)carve(256 * 4);
    float* c31     = (float*)carve(16 * 4);

    // one memset covers gcur (padded to 256) + lcnt3 (next carve slot)
    size_t gpad = ((size_t)NB * 4 + 255) & ~((size_t)255);
    hipMemsetAsync(gcur, 0, gpad + 16, stream);
    binfill_k<<<NBLK + 9, 1024, 0, stream>>>(src, dst, E, n, gcur, ovbuf, binsbuf, cnts,
                                             w1, w3, b3, fc1w, fc1b, fc2w, fc2b,
                                             M, cvec, W31, c31);

    int FB  = (n + 255) / 256;    // hop field blocks
    int FBJ = (n + 15) / 16;      // j-parallel proj/fieldsoft blocks
    int AB  = (n + 15) / 16;      // agg blocks (4 nodes/wave, 4 waves/block)
    // merged csr2 || proj (R30a): csr2's 391 starved blocks hide under
    // proj's 3125-block sea; both low-VGPR now (R24 contamination gone).
    csr2proj_k<<<NB + FBJ, 256, 0, stream>>>(binsbuf, cnts, gcur, ovbuf,
                                             csrp_s, nd_s, csr, be, lcnt3,
                                             x, buf0, buf1, out, w1, b1, w2, b2,
                                             W31, c31, M, cvec, n, NB);

    __half* cur = buf0;
    __half* nxt = buf1;
    // hop 1: agg only (field0 applied in proj)
    hop_k<<<AB, 256, 0, stream>>>(cur, nxt, out, csrp_s, nd_s, be, csr, lcnt3,
                                  w2, b1, b2, M, n, AB);
    { __half* t = cur; cur = nxt; nxt = t; }
    // hops 2..7: agg blocks first (critical path at t=0), field backfills
    for (int k = 1; k <= 6; k++) {
        hop_k<<<AB + FB, 256, 0, stream>>>(cur, nxt, out, csrp_s, nd_s, be, csr,
                                           lcnt3, w2, b1, b2, M + k * 128, n, AB);
        __half* t = cur; cur = nxt; nxt = t;
    }
    // final: field(z7, M7) + softmax (j-parallel, R30b)
    fieldsoft_k<<<FBJ, 256, 0, stream>>>(cur, out, w2, b1, b2, M + 7 * 128, n);
}

// Round 16
// 235.574 us; speedup vs baseline: 1.0542x; 1.0542x over previous
//
#include <hip/hip_runtime.h>
#include <hip/hip_fp16.h>

// ---------------------------------------------------------------------------
// LinearAggActor R35 (= R30/R33 exact, verified session best 235.0-236.8us):
//  - math (verified R2-R16): z0 = t2@(w3@w1)+b3@w1 (16-dim); z_k = A^k z0;
//    logits = cvec + sum_k relu(relu(z_k+b1)@w2+b2) @ M_k ; softmax.
//  - Measured landscape (sharply peaked at this config):
//    R20 gather-cut null; R24 epoch-cut ~0; R25 fp16 z +15; R26 ILP -11;
//    R27 occ caps -6; R29/R30 j-parallel starved roles +8; R30 csr2||proj
//    merge +5; R31 1-node/wave -40; R32 j-parallel overlapped role -27;
//    R34 agg-first order -12 (field-first = linear zin read WARMS L2 for
//    agg's random gathers + VALU overlap partner, m114).
//  - Config: csr2||proj merged role-split launch; j-parallel proj+fieldsoft
//    (16 lanes/node, shfl stages, xor-reduce); hop = field-first thread-per-
//    node + 4-nodes/wave tier-sorted agg (2-epoch chain), (256,4); fp16 z
//    rows + uint2 gathers, fp32 accumulate; binfill multisplit + setup.
//  - Both pipes <10% util: latency-bound across 10 dependent dispatches —
//    structural floor of this decomposition.
// ---------------------------------------------------------------------------

#define NB2MAX 400   // bins of 128 dsts: supports n <= 51200
#define NBLK   256   // binfill blocks
#define CAP2   32    // LDS staging per bin
#define CAPC   48    // per-(bin,block) cell capacity (mean 16, +8 sigma)
#define CAPB   6144  // per-bin dense CSR region (overflow tails only)
#define OVCAP  1024  // per-bin overflow region (statistically unused)
#define LCAP   6144  // csr2 per-bin LDS capacity (mean 4096, +32 sigma)
#define CAPN   64    // padded slots per node (mean 32, +5.7 sigma)

// blocks [0,NBLK): multisplit into private (bin,block) cells; packed
// (dloc<<16|src); LDS cursors; no global atomics on the hot path.
// blocks [NBLK, NBLK+9): setup role (R10-verified).
__global__ __launch_bounds__(1024) void binfill_k(
    const int* __restrict__ src, const int* __restrict__ dst, int E, int n,
    int* __restrict__ gcur, int* __restrict__ ovbuf,
    int* __restrict__ bins, int* __restrict__ cnts,
    const float* __restrict__ w1, const float* __restrict__ w3,
    const float* __restrict__ b3, const float* __restrict__ fc1w,
    const float* __restrict__ fc1b, const float* __restrict__ fc2w,
    const float* __restrict__ fc2b,
    float* __restrict__ M, float* __restrict__ cvec,
    float* __restrict__ W31, float* __restrict__ c31) {
    __shared__ int lbuf[NB2MAX * CAP2];
    __shared__ int lcnt[NB2MAX];
    __shared__ int lflush[NB2MAX];
    int tid = threadIdx.x;
    int NB = (n + 127) >> 7;

    if ((int)blockIdx.x >= NBLK) {
        // ---------------- setup role ----------------
        float* fl = (float*)lbuf;   // LDS reuse
        int s = (int)blockIdx.x - NBLK;
        if (s == 0) {
            if (tid < 256) {
                int i = tid >> 4, j = tid & 15;
                float a = 0.f;
                for (int g = 0; g < 64; g++) a += w3[i * 64 + g] * w1[g * 16 + j];
                W31[tid] = a;
            } else if (tid < 272) {
                int j = tid - 256;
                float a = 0.f;
                for (int g = 0; g < 64; g++) a += b3[g] * w1[g * 16 + j];
                c31[j] = a;
            } else if (tid >= 320 && tid < 384) {
                int h = tid - 320;
                float a = 0.f;
                for (int r = 0; r < 512; r++) a += b3[r & 63] * fc1w[r * 64 + h];
                fl[h] = a;   // u[h]
            }
            __syncthreads();
            if (tid < 8) {
                float a = fc2b[tid];
                for (int h = 0; h < 64; h++) a += (fc1b[h] + fl[h]) * fc2w[h * 8 + tid];
                cvec[tid] = a;
            }
        } else {
            int k = s - 1;
            {   // Q_k: one elem per thread
                int i = tid >> 6, h = tid & 63;
                float a = 0.f;
                const float* f1 = fc1w + (size_t)(k * 64) * 64 + h;
                for (int g = 0; g < 64; g++) a += w3[i * 64 + g] * f1[g * 64];
                fl[i * 64 + h] = a;
            }
            __syncthreads();
            if (tid < 128) {
                int i = tid >> 3, j = tid & 7;
                float a = 0.f;
                for (int h = 0; h < 64; h++) a += fl[i * 64 + h] * fc2w[h * 8 + j];
                M[k * 128 + i * 8 + j] = a;
            }
        }
        return;
    }

    // ---------------- binfill role ----------------
    for (int b = tid; b < NB; b += 1024) { lcnt[b] = 0; lflush[b] = 0; }
    __syncthreads();
    int blk = blockIdx.x;
    int chunk = (E + NBLK - 1) / NBLK;
    int beg = blk * chunk;
    int end = beg + chunk; if (end > E) end = E;
    for (int t0 = beg; t0 < end; t0 += 1024) {
        int e = t0 + tid;
        if (e < end) {
            int d = dst[e], s = src[e];
            if ((unsigned)d < (unsigned)n && (unsigned)s < (unsigned)n) {
                int b = d >> 7;
                int pk = ((d & 127) << 16) | s;
                int pos = atomicAdd(&lcnt[b], 1);
                if (pos < CAP2) lbuf[b * CAP2 + pos] = pk;
                else {  // statistically never
                    int p = atomicAdd(&gcur[b], 1);
                    if (p < OVCAP) ovbuf[b * OVCAP + p] = pk;
                }
            }
        }
        __syncthreads();
        for (int b = tid; b < NB; b += 1024) {
            int cnt = lcnt[b]; if (cnt > CAP2) cnt = CAP2;
            int fl2 = lflush[b];
            size_t cell = ((size_t)b * NBLK + blk) * CAPC;
            int base = 0;
            while (cnt - base >= 16) {
                if (fl2 + 16 <= CAPC) {
                    int* dp = bins + cell + fl2;
                    #pragma unroll
                    for (int q = 0; q < 16; q++) dp[q] = lbuf[b * CAP2 + base + q];
                    fl2 += 16;
                } else {  // cell overflow (statistically never)
                    int p = atomicAdd(&gcur[b], 16);
                    for (int q = 0; q < 16; q++)
                        if (p + q < OVCAP) ovbuf[b * OVCAP + p + q] = lbuf[b * CAP2 + base + q];
                }
                base += 16;
            }
            int rem = cnt - base;
            if (base > 0)
                for (int q = 0; q < rem; q++) lbuf[b * CAP2 + q] = lbuf[b * CAP2 + base + q];
            lcnt[b] = rem; lflush[b] = fl2;
        }
        __syncthreads();
    }
    for (int b = tid; b < NB; b += 1024) {
        int cnt = lcnt[b]; if (cnt > CAP2) cnt = CAP2;
        int fl2 = lflush[b];
        size_t cell = ((size_t)b * NBLK + blk) * CAPC;
        if (fl2 + cnt <= CAPC) {
            for (int q = 0; q < cnt; q++) bins[cell + fl2 + q] = lbuf[b * CAP2 + q];
            fl2 += cnt;
        } else {
            int p = atomicAdd(&gcur[b], cnt);
            for (int q = 0; q < cnt; q++)
                if (p + q < OVCAP) ovbuf[b * OVCAP + p + q] = lbuf[b * CAP2 + q];
        }
        cnts[(size_t)blk * NB + b] = fl2;
    }
}

// Merged launch (R30a). Blocks [0,NB): csr2 role (low VGPR, latency-bound,
// hides under proj's block sea). Blocks [NB, NB+FBJ): j-parallel proj role.
struct SmemC {   // csr2 role
    int hist[128], pref[128], cur[128], slot[128];
    int scnt[NBLK];
    int lbuf[LCAP];
    int sov;
    int ccnt[3], cbase[3];
};
struct SmemP {   // proj role
    float sx[16 * 68];
    float sw1[1024], sw2[256], sW[256], sM[128];
    float sb1[16], sb2[16], sc[16], scv[8];
};
union SmemU { SmemC c; SmemP p; };

__global__ __launch_bounds__(256) void csr2proj_k(
    const int* __restrict__ bins, const int* __restrict__ cnts,
    const int* __restrict__ gcur, const int* __restrict__ ovbuf,
    unsigned short* __restrict__ csrp_s, int2* __restrict__ nd_s,
    int* __restrict__ csr, int2* __restrict__ be, int* __restrict__ lcnt3,
    const float* __restrict__ x, __half* __restrict__ z0, __half* __restrict__ z1,
    float* __restrict__ logits,
    const float* __restrict__ w1, const float* __restrict__ b1,
    const float* __restrict__ w2, const float* __restrict__ b2,
    const float* __restrict__ W31, const float* __restrict__ c31,
    const float* __restrict__ M0, const float* __restrict__ cvec,
    int n, int NBARG) {
    __shared__ SmemU smem;
    int tid = threadIdx.x;
    if ((int)blockIdx.x < NBARG) {
        // ======================= csr2 role =======================
        SmemC& sc_ = smem.c;
        int NB = NBARG;
        int b = blockIdx.x;
        if (tid < 128) { sc_.hist[tid] = 0; sc_.cur[tid] = 0; }
        if (tid < 3) sc_.ccnt[tid] = 0;
        sc_.scnt[tid] = cnts[(size_t)tid * NB + b];
        if (tid == 0) {
            int g = gcur[b];
            sc_.sov = g < 0 ? 0 : (g > OVCAP ? OVCAP : g);
        }
        __syncthreads();
        {   // pass 1: histogram of dst-local
            int c = sc_.scnt[tid];
            size_t cell = ((size_t)b * NBLK + tid) * CAPC;
            for (int i = 0; i < c; i++) atomicAdd(&sc_.hist[bins[cell + i] >> 16], 1);
        }
        if (tid == 0)
            for (int i = 0; i < sc_.sov; i++)
                atomicAdd(&sc_.hist[ovbuf[b * OVCAP + i] >> 16], 1);
        __syncthreads();
        if (tid == 0) {
            int r = 0;
            for (int i = 0; i < 128; i++) { sc_.pref[i] = r; r += sc_.hist[i]; }
        }
        __syncthreads();
        {   // pass 2: place into LDS (bin-locally dense, sorted by dst)
            int c = sc_.scnt[tid];
            size_t cell = ((size_t)b * NBLK + tid) * CAPC;
            for (int i = 0; i < c; i++) {
                int pk = bins[cell + i];
                int dl = pk >> 16;
                int pos = sc_.pref[dl] + atomicAdd(&sc_.cur[dl], 1);
                if (pos < LCAP) sc_.lbuf[pos] = pk & 0xffff;
            }
        }
        if (tid == 0) {
            for (int i = 0; i < sc_.sov; i++) {
                int pk = ovbuf[b * OVCAP + i];
                int dl = pk >> 16;
                int pos = sc_.pref[dl] + atomicAdd(&sc_.cur[dl], 1);
                if (pos < LCAP) sc_.lbuf[pos] = pk & 0xffff;
            }
        }
        __syncthreads();
        // tier classification -> global sorted slot per node
        int myc = -1, lpos = 0;
        if (tid < 128) {
            int d = (b << 7) + tid;
            if (d < n) {
                int cnt = sc_.hist[tid];
                myc = cnt <= 32 ? 0 : (cnt <= 48 ? 1 : 2);
                lpos = atomicAdd(&sc_.ccnt[myc], 1);
            }
        }
        __syncthreads();
        if (tid < 3) sc_.cbase[tid] = atomicAdd(&lcnt3[tid], sc_.ccnt[tid]);
        __syncthreads();
        if (myc >= 0) {
            int d = (b << 7) + tid;
            int cnt = sc_.hist[tid];
            int s = myc * n + sc_.cbase[myc] + lpos;   // region base myc*n
            sc_.slot[tid] = s;
            nd_s[s] = make_int2(d, cnt);
            if (cnt > CAPN) {   // rare tail -> dense region + be (premult x4)
                int s0 = b * CAPB + sc_.pref[tid];
                be[d] = make_int2(s0 + CAPN, s0 + cnt);
                for (int j = CAPN; j < cnt; j++)
                    csr[s0 + j] = sc_.lbuf[sc_.pref[tid] + j] << 2;
            }
        }
        __syncthreads();
        // permuted padded ushort CSR into sorted row; sentinel = n (zero row)
        for (int q = tid; q < 128 * CAPN; q += 256) {
            int dl = q >> 6, j = q & 63;
            int d = (b << 7) + dl;
            if (d >= n) break;
            int cnt = sc_.hist[dl];
            int v = (j < cnt) ? sc_.lbuf[sc_.pref[dl] + j] : n;
            int pos = ((j & 3) << 4) | (j >> 2);
            csrp_s[(size_t)sc_.slot[dl] * CAPN + pos] = (unsigned short)v;
        }
        return;
    }
    // ======================= proj role (j-parallel, R29) =======================
    SmemP& sp = smem.p;
    for (int i = tid; i < 1024; i += 256) sp.sw1[i] = w1[i];
    sp.sw2[tid] = w2[tid];
    sp.sW[tid] = W31[tid];
    if (tid < 128) sp.sM[tid] = M0[tid];
    if (tid < 16) { sp.sb1[tid] = b1[tid]; sp.sb2[tid] = b2[tid]; sp.sc[tid] = c31[tid]; }
    if (tid < 8) sp.scv[tid] = cvec[tid];
    if ((int)blockIdx.x == NBARG && tid < 16) {   // zero sentinel row n
        ((unsigned short*)z0)[(size_t)n * 16 + tid] = 0;
        ((unsigned short*)z1)[(size_t)n * 16 + tid] = 0;
    }
    int node0 = ((int)blockIdx.x - NBARG) * 16;
    {   // stage x: 16 rows x 64 floats, coalesced float4
        int r = tid >> 4, c4 = tid & 15;
        if (node0 + r < n) {
            float4 v = ((const float4*)(x + (size_t)(node0 + r) * 64))[c4];
            float* dstp = sp.sx + r * 68 + c4 * 4;
            dstp[0] = v.x; dstp[1] = v.y; dstp[2] = v.z; dstp[3] = v.w;
        }
    }
    __syncthreads();
    int nl = tid >> 4, jj = tid & 15;
    int node = node0 + nl;
    if (node >= n) return;
    float t1 = 0.f;
    const float* xr = sp.sx + nl * 68;
    #pragma unroll
    for (int g = 0; g < 64; g++) t1 += xr[g] * sp.sw1[g * 16 + jj];
    t1 = fmaxf(t1 + sp.sb1[jj], 0.f);
    float t2 = sp.sb2[jj];
    #pragma unroll
    for (int i = 0; i < 16; i++) t2 += __shfl(t1, i, 16) * sp.sw2[i * 16 + jj];
    t2 = fmaxf(t2, 0.f);
    float zv = sp.sc[jj];
    #pragma unroll
    for (int i = 0; i < 16; i++) zv += __shfl(t2, i, 16) * sp.sW[i * 16 + jj];
    z0[(size_t)node * 16 + jj] = __float2half(zv);
    float hv = fmaxf(zv + sp.sb1[jj], 0.f);
    float f2 = sp.sb2[jj];
    #pragma unroll
    for (int i = 0; i < 16; i++) f2 += __shfl(hv, i, 16) * sp.sw2[i * 16 + jj];
    f2 = fmaxf(f2, 0.f);
    float p0 = f2 * sp.sM[jj * 8 + 0], p1 = f2 * sp.sM[jj * 8 + 1];
    float p2 = f2 * sp.sM[jj * 8 + 2], p3 = f2 * sp.sM[jj * 8 + 3];
    float p4 = f2 * sp.sM[jj * 8 + 4], p5 = f2 * sp.sM[jj * 8 + 5];
    float p6 = f2 * sp.sM[jj * 8 + 6], p7 = f2 * sp.sM[jj * 8 + 7];
    #pragma unroll
    for (int off = 1; off < 16; off <<= 1) {
        p0 += __shfl_xor(p0, off, 16); p1 += __shfl_xor(p1, off, 16);
        p2 += __shfl_xor(p2, off, 16); p3 += __shfl_xor(p3, off, 16);
        p4 += __shfl_xor(p4, off, 16); p5 += __shfl_xor(p5, off, 16);
        p6 += __shfl_xor(p6, off, 16); p7 += __shfl_xor(p7, off, 16);
    }
    if (jj < 8) {   // compile-time select chain (no runtime reg indexing)
        float myp = jj == 0 ? p0 : jj == 1 ? p1 : jj == 2 ? p2 : jj == 3 ? p3
                  : jj == 4 ? p4 : jj == 5 ? p5 : jj == 6 ? p6 : p7;
        logits[(size_t)node * 8 + jj] = sp.scv[jj] + myp;
    }
}

// unpack one uint2 (4 halfs = one channel quad) and accumulate
__device__ __forceinline__ void acc_row(uint2 u, float& ax, float& ay,
                                        float& az, float& aw) {
    __half2 p = *reinterpret_cast<const __half2*>(&u.x);
    __half2 q = *reinterpret_cast<const __half2*>(&u.y);
    float2 f = __half22float2(p), g = __half22float2(q);
    ax += f.x; ay += f.y; az += g.x; aw += g.y;
}

// One launch per hop. Blocks [0,FB): field(z_k) thread-per-node FIRST —
// linear zin sweep warms L2 for agg's random gathers + VALU overlap partner
// (R32 j-parallel -27us, R34 agg-first -12us: keep exactly this shape);
// blocks [FB,..): agg, 4 nodes/wave, tier-sorted rows, 2-epoch chain.
__global__ __launch_bounds__(256, 4) void hop_k(
    const __half* __restrict__ zin, __half* __restrict__ zout,
    float* __restrict__ logits,
    const unsigned short* __restrict__ csrp_s, const int2* __restrict__ nd_s,
    const int2* __restrict__ be, const int* __restrict__ csr,
    const int* __restrict__ lcnt3,
    const float* __restrict__ w2, const float* __restrict__ b1,
    const float* __restrict__ b2, const float* __restrict__ M, int n, int FB) {
    __shared__ float sw2[256], sM[128], sb1[16], sb2[16];
    int tid = threadIdx.x;
    if ((int)blockIdx.x < FB) {
        // ---- field role (thread-per-node) ----
        sw2[tid] = w2[tid];
        if (tid < 128) sM[tid] = M[tid];
        if (tid < 16) { sb1[tid] = b1[tid]; sb2[tid] = b2[tid]; }
        __syncthreads();
        int nid = blockIdx.x * 256 + tid;
        if (nid >= n) return;
        float h[16];
        const __half2* zp = (const __half2*)(zin + (size_t)nid * 16);
        #pragma unroll
        for (int q = 0; q < 8; q++) {
            float2 f = __half22float2(zp[q]);
            h[2 * q] = f.x; h[2 * q + 1] = f.y;
        }
        #pragma unroll
        for (int i = 0; i < 16; i++) h[i] = fmaxf(h[i] + sb1[i], 0.f);
        float t2[16];
        #pragma unroll
        for (int j = 0; j < 16; j++) {
            float a = sb2[j];
            #pragma unroll
            for (int i = 0; i < 16; i++) a += h[i] * sw2[i * 16 + j];
            t2[j] = fmaxf(a, 0.f);
        }
        float* lp = logits + (size_t)nid * 8;
        #pragma unroll
        for (int j = 0; j < 8; j++) {
            float l = 0.f;
            #pragma unroll
            for (int i = 0; i < 16; i++) l += t2[i] * sM[i * 8 + j];
            lp[j] += l;
        }
        return;
    }
    // ---- agg role: 4 nodes per wave, tier-sorted direct rows ----
    int wave = tid >> 6;
    int lane = tid & 63;
    int quarter = lane >> 4;              // which node of the 4
    int l16 = lane & 15;
    int t4 = l16 >> 2, ch = l16 & 3;      // slot-group 0..3, chan-quad 0..3
    int idx = (((int)blockIdx.x - FB) * 4 + wave) * 4 + quarter;
    if (idx >= n) return;
    int ns = lcnt3[0], nm = lcnt3[1];     // uniform scalar loads
    int tier; size_t row;
    if (idx < ns)           { tier = 0; row = (size_t)idx; }
    else if (idx < ns + nm) { tier = 1; row = (size_t)n + (idx - ns); }
    else                    { tier = 2; row = 2 * (size_t)n + (idx - ns - nm); }
    int2 nd = nd_s[row];                  // {node, deg} — same epoch as ip
    int node = nd.x, degi = nd.y;
    const uint4* ip = (const uint4*)(csrp_s + (row << 6));
    uint4 pa = ip[t4 * 2];                // sorted slots j = t4, t4+4, ..., t4+28
    int r0 = pa.x & 0xffff, r1 = pa.x >> 16;
    int r2 = pa.y & 0xffff, r3 = pa.y >> 16;
    int r4 = pa.z & 0xffff, r5 = pa.z >> 16;
    int r6 = pa.w & 0xffff, r7 = pa.w >> 16;
    const uint2* z2 = (const uint2*)zin;  // row stride = 4 uint2 (32B)
    uint2 u0 = z2[((size_t)r0 << 2) + ch];   // sentinel n -> zero row
    uint2 u1 = z2[((size_t)r1 << 2) + ch];
    uint2 u2 = z2[((size_t)r2 << 2) + ch];
    uint2 u3 = z2[((size_t)r3 << 2) + ch];
    uint2 u4 = z2[((size_t)r4 << 2) + ch];
    uint2 u5 = z2[((size_t)r5 << 2) + ch];
    uint2 u6 = z2[((size_t)r6 << 2) + ch];
    uint2 u7 = z2[((size_t)r7 << 2) + ch];
    float ax = 0.f, ay = 0.f, az = 0.f, aw = 0.f;
    acc_row(u0, ax, ay, az, aw); acc_row(u1, ax, ay, az, aw);
    acc_row(u2, ax, ay, az, aw); acc_row(u3, ax, ay, az, aw);
    acc_row(u4, ax, ay, az, aw); acc_row(u5, ax, ay, az, aw);
    acc_row(u6, ax, ay, az, aw); acc_row(u7, ax, ay, az, aw);
    if (tier >= 1) {
        uint4 pb = ip[t4 * 2 + 1];        // sorted slots j = t4+32..t4+60
        int r8 = pb.x & 0xffff, r9 = pb.x >> 16;
        int rA = pb.y & 0xffff, rB = pb.y >> 16;
        uint2 u8 = z2[((size_t)r8 << 2) + ch];
        uint2 u9 = z2[((size_t)r9 << 2) + ch];
        uint2 uA = z2[((size_t)rA << 2) + ch];
        uint2 uB = z2[((size_t)rB << 2) + ch];
        acc_row(u8, ax, ay, az, aw); acc_row(u9, ax, ay, az, aw);
        acc_row(uA, ax, ay, az, aw); acc_row(uB, ax, ay, az, aw);
        if (tier == 2) {
            int rC = pb.z & 0xffff, rD = pb.z >> 16;
            int rE = pb.w & 0xffff, rF = pb.w >> 16;
            uint2 uC = z2[((size_t)rC << 2) + ch];
            uint2 uD = z2[((size_t)rD << 2) + ch];
            uint2 uE = z2[((size_t)rE << 2) + ch];
            uint2 uF = z2[((size_t)rF << 2) + ch];
            acc_row(uC, ax, ay, az, aw); acc_row(uD, ax, ay, az, aw);
            acc_row(uE, ax, ay, az, aw); acc_row(uF, ax, ay, az, aw);
            if (degi > CAPN) {            // rare tail via dense csr (4 slots)
                int2 r = be[node];
                for (int q = r.x + t4; q < r.y; q += 4) {
                    uint2 u = z2[(size_t)csr[q] + ch];   // csr premult x4
                    acc_row(u, ax, ay, az, aw);
                }
            }
        }
    }
    // reduce over 4 slot-groups within this 16-lane quarter
    #pragma unroll
    for (int off = 8; off >= 4; off >>= 1) {
        ax += __shfl_down(ax, off, 16);
        ay += __shfl_down(ay, off, 16);
        az += __shfl_down(az, off, 16);
        aw += __shfl_down(aw, off, 16);
    }
    if (l16 < 4) {
        float inv = 1.f / (float)(degi > 0 ? degi : 1);
        __half2 h01 = __floats2half2_rn(ax * inv, ay * inv);
        __half2 h23 = __floats2half2_rn(az * inv, aw * inv);
        uint2 w;
        w.x = *reinterpret_cast<unsigned int*>(&h01);
        w.y = *reinterpret_cast<unsigned int*>(&h23);
        ((uint2*)(zout + (size_t)node * 16))[l16] = w;
    }
}

// final (R30b): logits += field(z7, M7); softmax. J-PARALLEL, 16 lanes/node.
__global__ __launch_bounds__(256, 4) void fieldsoft_k(
    const __half* __restrict__ z, float* __restrict__ logits,
    const float* __restrict__ w2, const float* __restrict__ b1,
    const float* __restrict__ b2, const float* __restrict__ M, int n) {
    __shared__ float sw2[256], sM[128], sb1[16], sb2[16];
    int tid = threadIdx.x;
    sw2[tid] = w2[tid];
    if (tid < 128) sM[tid] = M[tid];
    if (tid < 16) { sb1[tid] = b1[tid]; sb2[tid] = b2[tid]; }
    __syncthreads();
    int nl = tid >> 4, jj = tid & 15;
    int node = blockIdx.x * 16 + nl;
    if (node >= n) return;
    // lane jj loads z[node][jj]: 32B/node, contiguous 128B per 4-node wave
    float zv = __half2float(z[(size_t)node * 16 + jj]);
    float hv = fmaxf(zv + sb1[jj], 0.f);
    float t2 = sb2[jj];
    #pragma unroll
    for (int i = 0; i < 16; i++) t2 += __shfl(hv, i, 16) * sw2[i * 16 + jj];
    t2 = fmaxf(t2, 0.f);
    float p0 = t2 * sM[jj * 8 + 0], p1 = t2 * sM[jj * 8 + 1];
    float p2 = t2 * sM[jj * 8 + 2], p3 = t2 * sM[jj * 8 + 3];
    float p4 = t2 * sM[jj * 8 + 4], p5 = t2 * sM[jj * 8 + 5];
    float p6 = t2 * sM[jj * 8 + 6], p7 = t2 * sM[jj * 8 + 7];
    #pragma unroll
    for (int off = 1; off < 16; off <<= 1) {
        p0 += __shfl_xor(p0, off, 16); p1 += __shfl_xor(p1, off, 16);
        p2 += __shfl_xor(p2, off, 16); p3 += __shfl_xor(p3, off, 16);
        p4 += __shfl_xor(p4, off, 16); p5 += __shfl_xor(p5, off, 16);
        p6 += __shfl_xor(p6, off, 16); p7 += __shfl_xor(p7, off, 16);
    }
    // all 16 lanes now hold the full p0..p7. Lane jj works on logit q=jj&7
    // (lanes 8-15 mirror 0-7 so width-8 shuffles are well-defined).
    int q = jj & 7;
    float myp = q == 0 ? p0 : q == 1 ? p1 : q == 2 ? p2 : q == 3 ? p3
              : q == 4 ? p4 : q == 5 ? p5 : q == 6 ? p6 : p7;
    float lg = myp + logits[(size_t)node * 8 + q];
    float m = lg;
    m = fmaxf(m, __shfl_xor(m, 1, 8));
    m = fmaxf(m, __shfl_xor(m, 2, 8));
    m = fmaxf(m, __shfl_xor(m, 4, 8));
    float e = expf(lg - m);
    float s = e;
    s += __shfl_xor(s, 1, 8);
    s += __shfl_xor(s, 2, 8);
    s += __shfl_xor(s, 4, 8);
    if (jj < 8) logits[(size_t)node * 8 + jj] = e / s;
}

extern "C" void kernel_launch(void* const* d_in, const int* in_sizes, int n_in,
                              void* d_out, int out_size, void* d_ws, size_t ws_size,
                              hipStream_t stream) {
    const float* x    = (const float*)d_in[0];
    const int*   ei   = (const int*)d_in[1];
    const float* w1   = (const float*)d_in[2];
    const float* b1   = (const float*)d_in[3];
    const float* w2   = (const float*)d_in[4];
    const float* b2   = (const float*)d_in[5];
    const float* w3   = (const float*)d_in[6];
    const float* b3   = (const float*)d_in[7];
    const float* fc1w = (const float*)d_in[8];
    const float* fc1b = (const float*)d_in[9];
    const float* fc2w = (const float*)d_in[10];
    const float* fc2b = (const float*)d_in[11];
    float* out = (float*)d_out;

    int n = in_sizes[0] / 64;
    int E = in_sizes[1] / 2;
    int NB = (n + 127) >> 7;   // 391 for n=50000; NB <= NB2MAX
    const int* src = ei;
    const int* dst = ei + E;

    char* ws = (char*)d_ws;
    auto carve = [&](size_t bytes) {
        char* p = ws;
        ws += (bytes + 255) & ~((size_t)255);
        return p;
    };
    int*   gcur    = (int*)carve((size_t)NB * 4);
    int*   lcnt3   = (int*)carve(16);                 // contiguous after gcur pad
    int*   ovbuf   = (int*)carve((size_t)NB * OVCAP * 4);
    int*   binsbuf = (int*)carve((size_t)NB * NBLK * CAPC * 4);
    int*   cnts    = (int*)carve((size_t)NBLK * NB * 4);
    unsigned short* csrp_s = (unsigned short*)carve((size_t)3 * n * CAPN * 2); // tier-sorted
    int2*  nd_s    = (int2*)carve((size_t)3 * n * 8);                          // {node,deg}
    int*   csr     = (int*)carve((size_t)NB * CAPB * 4);
    int2*  be      = (int2*)carve((size_t)n * 8);
    __half* buf0   = (__half*)carve((size_t)(n + 1) * 16 * 2);  // +1 zero row
    __half* buf1   = (__half*)carve((size_t)(n + 1) * 16 * 2);
    float* M       = (float*)carve(1024 * 4);
    float* cvec    = (float*)carve(8 * 4);
    float* W31     = (float*)carve(256 * 4);
    float* c31     = (float*)carve(16 * 4);

    // one memset covers gcur (padded to 256) + lcnt3 (next carve slot)
    size_t gpad = ((size_t)NB * 4 + 255) & ~((size_t)255);
    hipMemsetAsync(gcur, 0, gpad + 16, stream);
    binfill_k<<<NBLK + 9, 1024, 0, stream>>>(src, dst, E, n, gcur, ovbuf, binsbuf, cnts,
                                             w1, w3, b3, fc1w, fc1b, fc2w, fc2b,
                                             M, cvec, W31, c31);

    int FB  = (n + 255) / 256;    // hop field blocks
    int FBJ = (n + 15) / 16;      // j-parallel proj/fieldsoft blocks
    int AB  = (n + 15) / 16;      // agg blocks (4 nodes/wave, 4 waves/block)
    // merged csr2 || proj (R30a): csr2's 391 starved blocks hide under
    // proj's 3125-block sea; both low-VGPR now (R24 contamination gone).
    csr2proj_k<<<NB + FBJ, 256, 0, stream>>>(binsbuf, cnts, gcur, ovbuf,
                                             csrp_s, nd_s, csr, be, lcnt3,
                                             x, buf0, buf1, out, w1, b1, w2, b2,
                                             W31, c31, M, cvec, n, NB);

    __half* cur = buf0;
    __half* nxt = buf1;
    // hop 1: agg only (field0 applied in proj)
    hop_k<<<AB, 256, 0, stream>>>(cur, nxt, out, csrp_s, nd_s, be, csr, lcnt3,
                                  w2, b1, b2, M, n, 0);
    { __half* t = cur; cur = nxt; nxt = t; }
    // hops 2..7: field(z_k, M_k) + agg(z_k -> z_{k+1}) in one launch
    for (int k = 1; k <= 6; k++) {
        hop_k<<<FB + AB, 256, 0, stream>>>(cur, nxt, out, csrp_s, nd_s, be, csr,
                                           lcnt3, w2, b1, b2, M + k * 128, n, FB);
        __half* t = cur; cur = nxt; nxt = t;
    }
    // final: field(z7, M7) + softmax (j-parallel, R30b)
    fieldsoft_k<<<FBJ, 256, 0, stream>>>(cur, out, w2, b1, b2, M + 7 * 128, n);
}